// Round 9
// baseline (157.663 us; speedup 1.0000x reference)
//
#include <hip/hip_runtime.h>
#include <math.h>

#define BATCH 8
#define T 1024
#define NH 8
#define NROW 8192
#define NEG_INF (-INFINITY)
#define SENT (-1.0e30f)
#define SC 0.180336880f      // 0.125 * log2(e)
#define LOG2E 1.442695041f

typedef __attribute__((ext_vector_type(8))) short short8;    // 8 bf16 (4 VGPRs)
typedef __attribute__((ext_vector_type(4))) float f32x4;

// fp32 -> bf16 (RNE)
__device__ __forceinline__ ushort f2bf(float x) {
  uint u = __float_as_uint(x);
  return (ushort)((u + 0x7FFFu + ((u >> 16) & 1u)) >> 16);
}
__device__ __forceinline__ uint pack2(float a, float b) {
  return (uint)f2bf(a) | ((uint)f2bf(b) << 16);
}
// async global->LDS, 16B per lane; LDS dest = wave-uniform base + lane*16
__device__ __forceinline__ void gl_lds16(const ushort* g, ushort* l) {
  __builtin_amdgcn_global_load_lds(
      (const __attribute__((address_space(1))) unsigned int*)g,
      (__attribute__((address_space(3))) unsigned int*)l, 16, 0, 0);
}

// ---------------------------------------------------------------- merged prep
// blocks [0,1024): prep_fg (bf16 pack + gate log-softmax)
// blocks [1024,1536): prep_w (Wq/Wk -> bf16 concat)
// blocks [1536,1544): n_valid
__global__ __launch_bounds__(256) void k_prep(
    const float* __restrict__ feat, const float* __restrict__ pos,
    const int* __restrict__ tokens,
    const float* __restrict__ Wq, const float* __restrict__ Wk,
    const float* __restrict__ Wg, const float* __restrict__ bg,
    ushort* __restrict__ fbf, ushort* __restrict__ Wbf,
    float* __restrict__ gout, int* __restrict__ nvout) {
  const int bid = blockIdx.x;
  const int tid = threadIdx.x;

  if (bid < 1024) {
    // ---- prep_fg
    __shared__ __align__(16) float Ws[8192];  // 8 x 1024 fp32 = 32 KB
#pragma unroll
    for (int u = 0; u < 8; ++u)
      ((float4*)Ws)[u * 256 + tid] = ((const float4*)Wg)[u * 256 + tid];
    __syncthreads();

    const int w = tid >> 6, l = tid & 63;
    const int c0 = l * 16;
    const int row0 = bid * 8 + w * 2;

    float4 f[2][4];
#pragma unroll
    for (int r = 0; r < 2; ++r) {
      const int row = row0 + r;
      const float* src = (c0 < 512) ? (feat + (size_t)row * 512 + c0)
                                    : (pos + (size_t)row * 512 + (c0 - 512));
#pragma unroll
      for (int q4 = 0; q4 < 4; ++q4) f[r][q4] = *(const float4*)(src + q4 * 4);
      uint4 o0, o1;
      o0.x = pack2(f[r][0].x, f[r][0].y); o0.y = pack2(f[r][0].z, f[r][0].w);
      o0.z = pack2(f[r][1].x, f[r][1].y); o0.w = pack2(f[r][1].z, f[r][1].w);
      o1.x = pack2(f[r][2].x, f[r][2].y); o1.y = pack2(f[r][2].z, f[r][2].w);
      o1.z = pack2(f[r][3].x, f[r][3].y); o1.w = pack2(f[r][3].z, f[r][3].w);
      *(uint4*)(fbf + (size_t)row * 1024 + c0) = o0;
      *(uint4*)(fbf + (size_t)row * 1024 + c0 + 8) = o1;
    }

    float s[2][8];
#pragma unroll
    for (int h = 0; h < 8; ++h) {
      const float* wg = Ws + h * 1024 + c0;
      float4 w0 = *(const float4*)(wg + 0);
      float4 w1 = *(const float4*)(wg + 4);
      float4 w2 = *(const float4*)(wg + 8);
      float4 w3 = *(const float4*)(wg + 12);
#pragma unroll
      for (int r = 0; r < 2; ++r)
        s[r][h] = f[r][0].x * w0.x + f[r][0].y * w0.y + f[r][0].z * w0.z + f[r][0].w * w0.w
                + f[r][1].x * w1.x + f[r][1].y * w1.y + f[r][1].z * w1.z + f[r][1].w * w1.w
                + f[r][2].x * w2.x + f[r][2].y * w2.y + f[r][2].z * w2.z + f[r][2].w * w2.w
                + f[r][3].x * w3.x + f[r][3].y * w3.y + f[r][3].z * w3.z + f[r][3].w * w3.w;
    }
#pragma unroll
    for (int m = 1; m < 64; m <<= 1)
#pragma unroll
      for (int r = 0; r < 2; ++r)
#pragma unroll
        for (int h = 0; h < 8; ++h) s[r][h] += __shfl_xor(s[r][h], m, 64);
    if (l == 0) {
#pragma unroll
      for (int r = 0; r < 2; ++r) {
        float lg[8], mx = -1e30f;
#pragma unroll
        for (int h = 0; h < 8; ++h) { lg[h] = s[r][h] + bg[h]; mx = fmaxf(mx, lg[h]); }
        float sum = 0.f;
#pragma unroll
        for (int h = 0; h < 8; ++h) sum += __expf(lg[h] - mx);
        const float lse = mx + __logf(sum);
#pragma unroll
        for (int h = 0; h < 8; ++h) gout[(size_t)(row0 + r) * 8 + h] = lg[h] - lse;
      }
    }
  } else if (bid < 1536) {
    // ---- prep_w
    const int gid = (bid - 1024) * 256 + tid;  // 0..131071
    const int e0 = gid * 8;
    const int n = e0 >> 10, k = e0 & 1023;
    const float* src = (n < 512) ? (Wq + (size_t)n * 1024 + k)
                                 : (Wk + (size_t)(n - 512) * 1024 + k);
    float4 a = *(const float4*)src;
    float4 b = *(const float4*)(src + 4);
    uint4 o;
    o.x = pack2(a.x, a.y); o.y = pack2(a.z, a.w);
    o.z = pack2(b.x, b.y); o.w = pack2(b.z, b.w);
    *(uint4*)(Wbf + (size_t)n * 1024 + k) = o;
  } else {
    // ---- n_valid
    const int b = bid - 1536;
    int cnt = 0;
    for (int i = tid; i < T; i += 256) cnt += (tokens[b * T + i] != 0) ? 1 : 0;
    __shared__ int s[256];
    s[tid] = cnt;
    __syncthreads();
    for (int st = 128; st > 0; st >>= 1) {
      if (tid < st) s[tid] += s[tid + st];
      __syncthreads();
    }
    if (tid == 0) nvout[b] = s[0];
  }
}

// ---------------------------------------------------------------- fused q/k GEMM (r8, unchanged)
// 128x128 tile, BK=64, 2-phase prefetch dbuf, T2 XOR-chunk swizzle, XCD swizzle,
// 512 threads / 8 waves (wave owns 64x32) -> 4 waves/SIMD.
__global__ __launch_bounds__(512, 4) void k_gemm(
    const ushort* __restrict__ fbf, const ushort* __restrict__ Wbf,
    const float* __restrict__ bq, const float* __restrict__ bk,
    ushort* __restrict__ qbuf, ushort* __restrict__ kbuf) {
  const int g = blockIdx.x + 8 * blockIdx.y;   // dispatch-linear id; xcd ~ g%8
  const int wid = (g & 7) * 64 + (g >> 3);     // bijective (512 = 8*64)
  const int n0 = (wid & 7) * 128;
  const int m0 = (wid >> 3) * 128;
  const int tid = threadIdx.x;
  const int w = tid >> 6, l = tid & 63;
  const int lo = l & 15, quad = l >> 4;
  const int wm0 = (w >> 2) * 64;   // wave m-offset: 0 or 64
  const int wn0 = (w & 3) * 32;    // wave n-offset: 0,32,64,96

  __shared__ ushort As[2][128 * 64];  // 2 x 16 KB, linear row-major [128][64]
  __shared__ ushort Bs[2][128 * 64];

  f32x4 acc[4][2];
#pragma unroll
  for (int i = 0; i < 4; ++i)
#pragma unroll
    for (int j = 0; j < 2; ++j) acc[i][j] = (f32x4){0.f, 0.f, 0.f, 0.f};

  const int csw = ((tid & 7) ^ ((tid >> 3) & 7)) * 8;
  const int r0 = tid >> 3;  // 0..63; dest rows u*64 + r0

  auto stage = [&](int buf, int k0) {
#pragma unroll
    for (int u = 0; u < 2; ++u) {
      gl_lds16(fbf + (size_t)(m0 + u * 64 + r0) * 1024 + k0 + csw,
               As[buf] + (size_t)(u * 512 + w * 64) * 8);
      gl_lds16(Wbf + (size_t)(n0 + u * 64 + r0) * 1024 + k0 + csw,
               Bs[buf] + (size_t)(u * 512 + w * 64) * 8);
    }
  };

  stage(0, 0);
  int cur = 0;
  for (int k0 = 0; k0 < 1024; k0 += 64) {
    __syncthreads();
    if (k0 + 64 < 1024) stage(cur ^ 1, k0 + 64);
    const ushort* pA = As[cur];
    const ushort* pB = Bs[cur];
#pragma unroll
    for (int kk = 0; kk < 2; ++kk) {
      const int swz = ((kk * 4 + quad) ^ (lo & 7)) * 8;
      short8 af[4], bfr[2];
#pragma unroll
      for (int mi = 0; mi < 4; ++mi)
        af[mi] = *(const short8*)(pA + (size_t)(wm0 + mi * 16 + lo) * 64 + swz);
#pragma unroll
      for (int ni = 0; ni < 2; ++ni)
        bfr[ni] = *(const short8*)(pB + (size_t)(wn0 + ni * 16 + lo) * 64 + swz);
#pragma unroll
      for (int mi = 0; mi < 4; ++mi)
#pragma unroll
        for (int ni = 0; ni < 2; ++ni)
          acc[mi][ni] = __builtin_amdgcn_mfma_f32_16x16x32_bf16(bfr[ni], af[mi], acc[mi][ni], 0, 0, 0);
    }
    cur ^= 1;
  }

  float4 bias4[2];
#pragma unroll
  for (int ni = 0; ni < 2; ++ni) {
    const int gn = n0 + wn0 + ni * 16 + quad * 4;
    bias4[ni] = *(const float4*)((gn < 512) ? (bq + gn) : (bk + gn - 512));
  }
#pragma unroll
  for (int mi = 0; mi < 4; ++mi) {
    const int m = m0 + wm0 + mi * 16 + lo;
#pragma unroll
    for (int ni = 0; ni < 2; ++ni) {
      const int gn = n0 + wn0 + ni * 16 + quad * 4;
      ushort* dst = (gn < 512) ? (qbuf + (size_t)m * 512 + gn)
                               : (kbuf + (size_t)m * 512 + gn - 512);
      ushort4 o;
      o.x = f2bf(acc[mi][ni][0] + bias4[ni].x);
      o.y = f2bf(acc[mi][ni][1] + bias4[ni].y);
      o.z = f2bf(acc[mi][ni][2] + bias4[ni].z);
      o.w = f2bf(acc[mi][ni][3] + bias4[ni].w);
      *(ushort4*)dst = o;
    }
  }
}

// ---------------------------------------------------------------- pass1 (unchanged)
__global__ __launch_bounds__(256) void k_pass1(
    const ushort* __restrict__ q, const ushort* __restrict__ kv,
    const float* __restrict__ g, const int* __restrict__ nvp,
    float* __restrict__ Wt) {
  const int b = blockIdx.x, h = blockIdx.y, it = blockIdx.z;
  const int nv = nvp[b];
  const int i0 = it * 64;
  const int tid = threadIdx.x;
  const int w = tid >> 6, l = tid & 63;
  const int lo = l & 15, quad = l >> 4;

  __shared__ ushort Ks[2][64 * 64];  // 2 x 8 KB

  const int i = i0 + w * 16 + lo;
  const ushort* qp = q + (size_t)(b * T + i) * 512 + h * 64 + quad * 8;
  const short8 a0 = *(const short8*)qp;
  const short8 a1 = *(const short8*)(qp + 32);

  float lsum = 0.f;
  const int ntile = ((nv + 63) >> 6) - it;

  if (ntile > 0) {
    auto stage = [&](int buf, int jt) {
#pragma unroll
      for (int u = 0; u < 2; ++u) {
        const int s = u * 256 + tid;
        const int row = s >> 3, c = s & 7;
        gl_lds16(kv + (size_t)(b * T + jt * 64 + row) * 512 + h * 64 + ((c ^ (row & 7)) * 8),
                 Ks[buf] + (size_t)(u * 256 + w * 64) * 8);
      }
    };
    stage(0, it);
    __syncthreads();
    for (int s = 0; s < ntile; ++s) {
      if (s + 1 < ntile) stage((s + 1) & 1, it + s + 1);
      const ushort* kbase = Ks[s & 1];
      const int j0 = (it + s) * 64;
      const bool diag = (s == 0);
      const bool masked = diag | (j0 + 64 > nv);
#pragma unroll
      for (int ni = 0; ni < 4; ++ni) {
        if (diag && ni < w) continue;  // sub-tile fully below diagonal (wave-uniform)
        const int rw = ni * 16 + lo;
        const short8 b0 = *(const short8*)(kbase + (size_t)rw * 64 + ((quad ^ (rw & 7)) * 8));
        const short8 b1 = *(const short8*)(kbase + (size_t)rw * 64 + (((4 + quad) ^ (rw & 7)) * 8));
        f32x4 acc = (f32x4){0.f, 0.f, 0.f, 0.f};
        acc = __builtin_amdgcn_mfma_f32_16x16x32_bf16(b0, a0, acc, 0, 0, 0);
        acc = __builtin_amdgcn_mfma_f32_16x16x32_bf16(b1, a1, acc, 0, 0, 0);
        if (!masked) {
#pragma unroll
          for (int r = 0; r < 4; ++r) lsum += __builtin_amdgcn_exp2f(acc[r] * SC);
        } else {
          const int jb = j0 + ni * 16 + quad * 4;
#pragma unroll
          for (int r = 0; r < 4; ++r) {
            const int j = jb + r;
            if (j > i && j < nv) lsum += __builtin_amdgcn_exp2f(acc[r] * SC);
          }
        }
      }
      __syncthreads();
    }
  }

  lsum += __shfl_xor(lsum, 16, 64);
  lsum += __shfl_xor(lsum, 32, 64);
  if (quad == 0) {
    const size_t row = (size_t)(b * T) + i;
    Wt[(size_t)h * NROW + row] =
        (lsum > 0.f) ? (g[row * 8 + h] - __logf(lsum)) : NEG_INF;
  }
}

// ---------------------------------------------------------------- pass2: 64x128 tiles, 4 waves
// NEW (r9): 256 threads, K-only LDS per-head dbuf (2x16 KB = 32 KB -> ~5 blocks/CU),
// Q fragments direct from XCD-local L2 (pass1-proven pattern, 2 loads/head hidden
// under 16 ds_read + 16 MFMA + 32 exp2). Same swizzle involution / mask / store
// formulas as r3-r8 (verified). blockIdx.x = b -> XCD-local.
__global__ __launch_bounds__(256) void k_pass2(
    const ushort* __restrict__ q, const ushort* __restrict__ kv,
    const float* __restrict__ Wt, const int* __restrict__ nvp,
    float* __restrict__ out) {
  const int b = blockIdx.x, jt = blockIdx.y, it = blockIdx.z;
  const int nv = nvp[b];
  const int i0 = it * 64, j0 = jt * 128;
  const int tid = threadIdx.x;

  if (j0 + 127 <= i0 || j0 >= nv) {
    // whole tile has j <= i (or j >= nv): SENT fill 64 x 128
    const int r0 = tid >> 5, c0 = (tid & 31) * 4;
    float4 v; v.x = v.y = v.z = v.w = SENT;
#pragma unroll
    for (int u = 0; u < 8; ++u)
      *(float4*)(out + ((size_t)(b * T + i0 + r0 + u * 8)) * T + j0 + c0) = v;
    return;
  }

  const int wv = tid >> 6, l = tid & 63;
  const int lo = l & 15, quad = l >> 4;
  const int i = i0 + wv * 16 + lo;

  __shared__ ushort Ks[2][128 * 64];  // 2 x 16 KB

  auto stage = [&](int buf, int h) {
#pragma unroll
    for (int u = 0; u < 4; ++u) {
      const int s = u * 256 + tid;        // 0..1023 chunk id
      const int row = s >> 3, c = s & 7;  // row 0..127, chunk 0..7
      gl_lds16(kv + (size_t)(b * T + j0 + row) * 512 + h * 64 + ((c ^ (row & 7)) * 8),
               Ks[buf] + (size_t)(u * 256 + wv * 64) * 8);
    }
  };

  stage(0, 0);  // head 0 in flight

  // per-row weights (lane-local row i)
  const ushort* qb = q + (size_t)(b * T + i) * 512 + quad * 8;
  float wl[8];
#pragma unroll
  for (int h = 0; h < 8; ++h)
    wl[h] = Wt[(size_t)h * NROW + b * T + i] * LOG2E;  // -inf stays -inf

  float se[8][4];  // [ni][r], j = j0 + ni*16 + quad*4 + r
#pragma unroll
  for (int a = 0; a < 8; ++a)
#pragma unroll
    for (int r = 0; r < 4; ++r) se[a][r] = 0.f;

  __syncthreads();  // head-0 staging complete

#pragma unroll
  for (int h = 0; h < 8; ++h) {
    if (h < 7) stage((h + 1) & 1, h + 1);  // prefetch next head under this compute
    const ushort* kbase = Ks[h & 1];
    const short8 a0 = *(const short8*)(qb + h * 64);        // L2-hit, hidden by TLP
    const short8 a1 = *(const short8*)(qb + h * 64 + 32);
#pragma unroll
    for (int ni = 0; ni < 8; ++ni) {
      const int rw = ni * 16 + lo;
      const short8 b0 = *(const short8*)(kbase + (size_t)rw * 64 + ((quad ^ (rw & 7)) * 8));
      const short8 b1 = *(const short8*)(kbase + (size_t)rw * 64 + (((4 + quad) ^ (rw & 7)) * 8));
      f32x4 acc = (f32x4){0.f, 0.f, 0.f, 0.f};
      acc = __builtin_amdgcn_mfma_f32_16x16x32_bf16(b0, a0, acc, 0, 0, 0);
      acc = __builtin_amdgcn_mfma_f32_16x16x32_bf16(b1, a1, acc, 0, 0, 0);
#pragma unroll
      for (int r = 0; r < 4; ++r)
        se[ni][r] += __builtin_amdgcn_exp2f(acc[r] * SC + wl[h]);
    }
    if (h < 7) __syncthreads();  // next-head staging drained + buffer reuse safe
  }

  // epilogue: lane owns row i; per (ni) 4 consecutive j -> float4 stores
  const size_t orow = ((size_t)(b * T + i)) * T;
  const bool maskfree = (j0 >= i0 + 64) && (j0 + 128 <= nv);
  if (maskfree) {
#pragma unroll
    for (int ni = 0; ni < 8; ++ni) {
      const int jb = j0 + ni * 16 + quad * 4;
      float4 v;
      v.x = fmaxf(__logf(se[ni][0]), SENT);
      v.y = fmaxf(__logf(se[ni][1]), SENT);
      v.z = fmaxf(__logf(se[ni][2]), SENT);
      v.w = fmaxf(__logf(se[ni][3]), SENT);
      *(float4*)(out + orow + jb) = v;
    }
  } else {
#pragma unroll
    for (int ni = 0; ni < 8; ++ni) {
      const int jb = j0 + ni * 16 + quad * 4;
      float4 v;
      v.x = (jb + 0 > i && jb + 0 < nv) ? fmaxf(__logf(se[ni][0]), SENT) : SENT;
      v.y = (jb + 1 > i && jb + 1 < nv) ? fmaxf(__logf(se[ni][1]), SENT) : SENT;
      v.z = (jb + 2 > i && jb + 2 < nv) ? fmaxf(__logf(se[ni][2]), SENT) : SENT;
      v.w = (jb + 3 > i && jb + 3 < nv) ? fmaxf(__logf(se[ni][3]), SENT) : SENT;
      *(float4*)(out + orow + jb) = v;
    }
  }
}

// ---------------------------------------------------------------- launch
extern "C" void kernel_launch(void* const* d_in, const int* in_sizes, int n_in,
                              void* d_out, int out_size, void* d_ws, size_t ws_size,
                              hipStream_t stream) {
  (void)in_sizes; (void)n_in; (void)out_size; (void)ws_size;
  const float* feat = (const float*)d_in[0];
  const float* pos  = (const float*)d_in[1];
  const int* tokens = (const int*)d_in[2];
  const float* Wq = (const float*)d_in[3];
  const float* bq = (const float*)d_in[4];
  const float* Wk = (const float*)d_in[5];
  const float* bk = (const float*)d_in[6];
  const float* Wg = (const float*)d_in[7];
  const float* bg = (const float*)d_in[8];
  float* out = (float*)d_out;

  // workspace: qbuf 8.4M | kbuf 8.4M | Wbf 2M | gbuf 256K | Wt 256K | nv
  ushort* qbuf = (ushort*)d_ws;
  ushort* kbuf = qbuf + (size_t)NROW * 512;
  ushort* Wbf  = kbuf + (size_t)NROW * 512;
  float*  gbuf = (float*)(Wbf + (size_t)1024 * 1024);
  float*  Wt   = gbuf + (size_t)NROW * NH;
  int*    nv   = (int*)(Wt + (size_t)NH * NROW);

  // fbf (bf16 concat of feat,pos) lives in d_out; consumed by k_gemm,
  // fully overwritten later by k_pass2.
  ushort* fbf = (ushort*)d_out;

  k_prep<<<dim3(1544), dim3(256), 0, stream>>>(feat, pos, tokens, Wq, Wk, Wg, bg,
                                               fbf, Wbf, gbuf, nv);
  k_gemm<<<dim3(8, 64), dim3(512), 0, stream>>>(fbf, Wbf, bq, bk, qbuf, kbuf);
  k_pass1<<<dim3(BATCH, NH, 16), dim3(256), 0, stream>>>(qbuf, kbuf, gbuf, nv, Wt);
  k_pass2<<<dim3(BATCH, 8, 16), dim3(256), 0, stream>>>(qbuf, kbuf, Wt, nv, out);
}